// Round 1
// baseline (604.540 us; speedup 1.0000x reference)
//
#include <hip/hip_runtime.h>
#include <math.h>

#define NN 50000
#define NE 800000
#define D 64
#define NC 40

// ---------------- degree / normalization ----------------

__global__ void init_deg(float* __restrict__ deg) {
    int i = blockIdx.x * blockDim.x + threadIdx.x;
    if (i < NN) deg[i] = 1.0f;  // self-loop contributes 1
}

__global__ void count_deg(const int* __restrict__ ei, float* __restrict__ deg) {
    int e = blockIdx.x * blockDim.x + threadIdx.x;
    if (e < NE) {
        int dst = ei[NE + e];
        atomicAdd(&deg[dst], 1.0f);
    }
}

__global__ void finalize_dinv(float* __restrict__ deg) {
    int i = blockIdx.x * blockDim.x + threadIdx.x;
    if (i < NN) deg[i] = rsqrtf(deg[i]);  // deg >= 1 always (self-loops)
}

// ---------------- dense transforms ----------------

// C[NN,64] = A[NN,64] @ W[64,64]; 4 rows per 256-thread block, W staged in LDS.
__global__ __launch_bounds__(256) void gemm64(const float* __restrict__ A,
                                              const float* __restrict__ W,
                                              float* __restrict__ C) {
    __shared__ float Ws[64 * 64];
    __shared__ float As[4 * 64];
    int tid = threadIdx.x;
    for (int i = tid; i < 64 * 64; i += 256) Ws[i] = W[i];
    int r = tid >> 6, c = tid & 63;
    int row = blockIdx.x * 4 + r;
    if (row < NN) As[r * 64 + c] = A[row * 64 + c];
    __syncthreads();
    if (row < NN) {
        float acc = 0.0f;
#pragma unroll
        for (int k = 0; k < 64; ++k) acc += As[r * 64 + k] * Ws[k * 64 + c];
        C[row * 64 + c] = acc;
    }
}

// out[NN,40] = h[NN,64] @ Wc[64,40] + bc
__global__ __launch_bounds__(256) void classifier(const float* __restrict__ h,
                                                  const float* __restrict__ Wc,
                                                  const float* __restrict__ bc,
                                                  float* __restrict__ out) {
    __shared__ float Ws[64 * NC];
    __shared__ float bs[NC];
    int tid = threadIdx.x;
    for (int i = tid; i < 64 * NC; i += 256) Ws[i] = Wc[i];
    if (tid < NC) bs[tid] = bc[tid];
    __syncthreads();
    int idx = blockIdx.x * 256 + tid;
    if (idx < NN * NC) {
        int row = idx / NC;
        int col = idx - row * NC;
        const float* hr = h + row * 64;
        float acc = bs[col];
#pragma unroll
        for (int k = 0; k < 64; ++k) acc += hr[k] * Ws[k * NC + col];
        out[idx] = acc;
    }
}

// ---------------- aggregation ----------------

// agg[i,:] = h[i,:] * dinv[i]^2   (self-loop message; also zero-initializes agg)
__global__ void self_init(const float* __restrict__ h, const float* __restrict__ dinv,
                          float* __restrict__ agg) {
    int idx = blockIdx.x * blockDim.x + threadIdx.x;
    if (idx < NN * D) {
        float di = dinv[idx >> 6];
        agg[idx] = h[idx] * di * di;
    }
}

// one wave per edge: lane d does agg[dst,d] += h[src,d]*dinv[src]*dinv[dst]
__global__ __launch_bounds__(256) void scatter_edges(const int* __restrict__ ei,
                                                     const float* __restrict__ h,
                                                     const float* __restrict__ dinv,
                                                     float* __restrict__ agg) {
    int e = blockIdx.x * 4 + (threadIdx.x >> 6);
    int d = threadIdx.x & 63;
    if (e < NE) {
        int s = ei[e];
        int t = ei[NE + e];
        float norm = dinv[s] * dinv[t];
        atomicAdd(&agg[t * 64 + d], h[s * 64 + d] * norm);
    }
}

__global__ void bias_tanh(const float* __restrict__ agg, const float* __restrict__ b,
                          float* __restrict__ out) {
    int idx = blockIdx.x * blockDim.x + threadIdx.x;
    if (idx < NN * D) out[idx] = tanhf(agg[idx] + b[idx & 63]);
}

// ---------------- launch ----------------

extern "C" void kernel_launch(void* const* d_in, const int* in_sizes, int n_in,
                              void* d_out, int out_size, void* d_ws, size_t ws_size,
                              hipStream_t stream) {
    const float* x  = (const float*)d_in[0];
    const int*   ei = (const int*)d_in[1];   // edge_index [2,E] per harness int contract
    const float* W1 = (const float*)d_in[2];
    const float* b1 = (const float*)d_in[3];
    const float* W2 = (const float*)d_in[4];
    const float* b2 = (const float*)d_in[5];
    const float* Wc = (const float*)d_in[6];
    const float* bc = (const float*)d_in[7];

    float* out   = (float*)d_out;            // [NN, 40]
    float* h_out = out + NN * NC;            // [NN, 64]

    float* dinv = (float*)d_ws;              // NN
    float* bufA = dinv + NN;                 // NN*64 : XW result
    float* bufB = bufA + NN * D;             // NN*64 : agg / tanh result

    const int elemBlocks = (NN * D + 255) / 256;   // 12500
    const int nodeBlocks = (NN + 255) / 256;
    const int edgeBlocks = (NE + 255) / 256;
    const int scatBlocks = (NE + 3) / 4;           // 4 edges (waves) per block

    // normalization
    init_deg<<<nodeBlocks, 256, 0, stream>>>(dinv);
    count_deg<<<edgeBlocks, 256, 0, stream>>>(ei, dinv);
    finalize_dinv<<<nodeBlocks, 256, 0, stream>>>(dinv);

    // layer 1
    gemm64<<<(NN + 3) / 4, 256, 0, stream>>>(x, W1, bufA);
    self_init<<<elemBlocks, 256, 0, stream>>>(bufA, dinv, bufB);
    scatter_edges<<<scatBlocks, 256, 0, stream>>>(ei, bufA, dinv, bufB);
    bias_tanh<<<elemBlocks, 256, 0, stream>>>(bufB, b1, bufB);

    // layer 2
    gemm64<<<(NN + 3) / 4, 256, 0, stream>>>(bufB, W2, bufA);
    self_init<<<elemBlocks, 256, 0, stream>>>(bufA, dinv, bufB);
    scatter_edges<<<scatBlocks, 256, 0, stream>>>(ei, bufA, dinv, bufB);
    bias_tanh<<<elemBlocks, 256, 0, stream>>>(bufB, b2, h_out);

    // classifier
    classifier<<<(NN * NC + 255) / 256, 256, 0, stream>>>(h_out, Wc, bc, out);
}

// Round 2
// 482.338 us; speedup vs baseline: 1.2534x; 1.2534x over previous
//
#include <hip/hip_runtime.h>
#include <math.h>

#define NN 50000
#define NE 800000
#define D 64
#define NC 40

// ---------------- CSR build ----------------

__global__ void count_deg(const int* __restrict__ ei, int* __restrict__ cnt) {
    int e = blockIdx.x * blockDim.x + threadIdx.x;
    if (e < NE) atomicAdd(&cnt[ei[NE + e]], 1);
}

// Single workgroup: exclusive-scan 50000 counts -> rowStart, init cursor,
// and compute dinv[i] = rsqrt(deg_in + 1) (the +1 is the self-loop).
__global__ __launch_bounds__(1024) void scan_build(const int* __restrict__ cnt,
                                                   int* __restrict__ rowStart,
                                                   int* __restrict__ cursor,
                                                   float* __restrict__ dinv) {
    __shared__ int sums[1024];
    const int CH = (NN + 1023) / 1024;  // 49
    int t = threadIdx.x;
    int beg = t * CH, end = min(beg + CH, NN);
    int s = 0;
    for (int i = beg; i < end; ++i) s += cnt[i];
    sums[t] = s;
    __syncthreads();
    for (int off = 1; off < 1024; off <<= 1) {
        int v = (t >= off) ? sums[t - off] : 0;
        __syncthreads();
        sums[t] += v;
        __syncthreads();
    }
    int run = (t == 0) ? 0 : sums[t - 1];
    for (int i = beg; i < end; ++i) {
        int c = cnt[i];
        rowStart[i] = run;
        cursor[i] = run;
        dinv[i] = rsqrtf((float)c + 1.0f);
        run += c;
    }
    if (t == 0) rowStart[NN] = NE;
}

__global__ void fill_csr(const int* __restrict__ ei, int* __restrict__ cursor,
                         int* __restrict__ csr) {
    int e = blockIdx.x * blockDim.x + threadIdx.x;
    if (e < NE) {
        int s = ei[e];
        int t = ei[NE + e];
        int pos = atomicAdd(&cursor[t], 1);
        csr[pos] = s;
    }
}

// ---------------- dense transforms ----------------

// C[row,:] = (A[row,:] @ W) * dinv[row]   -- pre-scales messages by dinv[src]
__global__ __launch_bounds__(256) void gemm64_scaled(const float* __restrict__ A,
                                                     const float* __restrict__ W,
                                                     const float* __restrict__ dinv,
                                                     float* __restrict__ C) {
    __shared__ float Ws[64 * 64];
    __shared__ float As[4 * 64];
    int tid = threadIdx.x;
    for (int i = tid; i < 64 * 64; i += 256) Ws[i] = W[i];
    int r = tid >> 6, c = tid & 63;
    int row = blockIdx.x * 4 + r;
    if (row < NN) As[r * 64 + c] = A[row * 64 + c];
    __syncthreads();
    if (row < NN) {
        float acc = 0.0f;
#pragma unroll
        for (int k = 0; k < 64; ++k) acc += As[r * 64 + k] * Ws[k * 64 + c];
        C[row * 64 + c] = acc * dinv[row];
    }
}

// out[NN,40] = h[NN,64] @ Wc[64,40] + bc
__global__ __launch_bounds__(256) void classifier(const float* __restrict__ h,
                                                  const float* __restrict__ Wc,
                                                  const float* __restrict__ bc,
                                                  float* __restrict__ out) {
    __shared__ float Ws[64 * NC];
    __shared__ float bs[NC];
    int tid = threadIdx.x;
    for (int i = tid; i < 64 * NC; i += 256) Ws[i] = Wc[i];
    if (tid < NC) bs[tid] = bc[tid];
    __syncthreads();
    int idx = blockIdx.x * 256 + tid;
    if (idx < NN * NC) {
        int row = idx / NC;
        int col = idx - row * NC;
        const float* hr = h + row * 64;
        float acc = bs[col];
#pragma unroll
        for (int k = 0; k < 64; ++k) acc += hr[k] * Ws[k * NC + col];
        out[idx] = acc;
    }
}

// ---------------- aggregation (gather form) ----------------

// One wave per node, lane d owns dim d.
// hs rows are already scaled by dinv[src] (gemm epilogue); self term is hs[node].
// out = tanh( dinv[node] * (hs[node] + sum_{src in-edges} hs[src]) + b )
__global__ __launch_bounds__(256) void gather_tanh(const int* __restrict__ rowStart,
                                                   const int* __restrict__ csr,
                                                   const float* __restrict__ hs,
                                                   const float* __restrict__ dinv,
                                                   const float* __restrict__ b,
                                                   float* __restrict__ out) {
    int node = blockIdx.x * 4 + (threadIdx.x >> 6);
    int d = threadIdx.x & 63;
    if (node >= NN) return;
    int beg = rowStart[node], end = rowStart[node + 1];
    float acc0 = hs[node * 64 + d];  // self-loop (already *dinv[node])
    float acc1 = 0.0f;
    int e = beg;
    for (; e + 1 < end; e += 2) {  // two independent chains for latency overlap
        int s0 = csr[e];
        int s1 = csr[e + 1];
        acc0 += hs[s0 * 64 + d];
        acc1 += hs[s1 * 64 + d];
    }
    if (e < end) acc1 += hs[csr[e] * 64 + d];
    out[node * 64 + d] = tanhf((acc0 + acc1) * dinv[node] + b[d]);
}

// ---------------- launch ----------------

extern "C" void kernel_launch(void* const* d_in, const int* in_sizes, int n_in,
                              void* d_out, int out_size, void* d_ws, size_t ws_size,
                              hipStream_t stream) {
    const float* x  = (const float*)d_in[0];
    const int*   ei = (const int*)d_in[1];
    const float* W1 = (const float*)d_in[2];
    const float* b1 = (const float*)d_in[3];
    const float* W2 = (const float*)d_in[4];
    const float* b2 = (const float*)d_in[5];
    const float* Wc = (const float*)d_in[6];
    const float* bc = (const float*)d_in[7];

    float* out   = (float*)d_out;   // [NN, 40]
    float* h_out = out + NN * NC;   // [NN, 64]

    // workspace layout (all 4-byte elements)
    float* dinv     = (float*)d_ws;            // NN
    int*   cnt      = (int*)(dinv + NN);       // NN
    int*   rowStart = cnt + NN;                // NN+1
    int*   cursor   = rowStart + NN + 1;       // NN
    int*   csr      = cursor + NN;             // NE
    float* bufA     = (float*)(csr + NE);      // NN*D
    float* bufB     = bufA + NN * D;           // NN*D

    const int edgeBlocks = (NE + 255) / 256;
    const int nodeBlocks4 = (NN + 3) / 4;      // 12500

    // CSR + normalization (once; reused by both layers)
    hipMemsetAsync(cnt, 0, NN * sizeof(int), stream);
    count_deg<<<edgeBlocks, 256, 0, stream>>>(ei, cnt);
    scan_build<<<1, 1024, 0, stream>>>(cnt, rowStart, cursor, dinv);
    fill_csr<<<edgeBlocks, 256, 0, stream>>>(ei, cursor, csr);

    // layer 1
    gemm64_scaled<<<nodeBlocks4, 256, 0, stream>>>(x, W1, dinv, bufA);
    gather_tanh<<<nodeBlocks4, 256, 0, stream>>>(rowStart, csr, bufA, dinv, b1, bufB);

    // layer 2
    gemm64_scaled<<<nodeBlocks4, 256, 0, stream>>>(bufB, W2, dinv, bufA);
    gather_tanh<<<nodeBlocks4, 256, 0, stream>>>(rowStart, csr, bufA, dinv, b2, h_out);

    // classifier
    classifier<<<(NN * NC + 255) / 256, 256, 0, stream>>>(h_out, Wc, bc, out);
}

// Round 3
// 358.605 us; speedup vs baseline: 1.6858x; 1.3450x over previous
//
#include <hip/hip_runtime.h>
#include <math.h>

#define NN 50000
#define NE 800000
#define D 64
#define NC 40
#define NB_SCAN 196  // ceil(NN/256)

// ---------------- CSR build ----------------

__global__ void count_deg(const int* __restrict__ ei, int* __restrict__ cnt) {
    int e = blockIdx.x * blockDim.x + threadIdx.x;
    if (e < NE) atomicAdd(&cnt[ei[NE + e]], 1);
}

// Phase A: per-block sums of 256-element chunks of cnt.
__global__ __launch_bounds__(256) void scan_sums(const int* __restrict__ cnt,
                                                 int* __restrict__ partial) {
    __shared__ int s[256];
    int t = threadIdx.x;
    int i = blockIdx.x * 256 + t;
    s[t] = (i < NN) ? cnt[i] : 0;
    __syncthreads();
    for (int off = 128; off > 0; off >>= 1) {
        if (t < off) s[t] += s[t + off];
        __syncthreads();
    }
    if (t == 0) partial[blockIdx.x] = s[0];
}

// Phase B: single small block turns partial sums into exclusive block offsets.
__global__ __launch_bounds__(256) void scan_partials(int* __restrict__ partial) {
    __shared__ int s[256];
    int t = threadIdx.x;
    int v = (t < NB_SCAN) ? partial[t] : 0;
    s[t] = v;
    __syncthreads();
    for (int off = 1; off < 256; off <<= 1) {
        int u = (t >= off) ? s[t - off] : 0;
        __syncthreads();
        s[t] += u;
        __syncthreads();
    }
    if (t < NB_SCAN) partial[t] = s[t] - v;  // exclusive
}

// Phase C: local exclusive scan + block offset; emit rowStart, cursor, dinv.
__global__ __launch_bounds__(256) void scan_final(const int* __restrict__ cnt,
                                                  const int* __restrict__ partial,
                                                  int* __restrict__ rowStart,
                                                  int* __restrict__ cursor,
                                                  float* __restrict__ dinv) {
    __shared__ int s[256];
    int t = threadIdx.x;
    int i = blockIdx.x * 256 + t;
    int v = (i < NN) ? cnt[i] : 0;
    s[t] = v;
    __syncthreads();
    for (int off = 1; off < 256; off <<= 1) {
        int u = (t >= off) ? s[t - off] : 0;
        __syncthreads();
        s[t] += u;
        __syncthreads();
    }
    if (i < NN) {
        int excl = partial[blockIdx.x] + s[t] - v;
        rowStart[i] = excl;
        cursor[i] = excl;
        dinv[i] = rsqrtf((float)v + 1.0f);
    }
    if (i == 0) rowStart[NN] = NE;
}

__global__ void fill_csr(const int* __restrict__ ei, int* __restrict__ cursor,
                         int* __restrict__ csr) {
    int e = blockIdx.x * blockDim.x + threadIdx.x;
    if (e < NE) {
        int s = ei[e];
        int t = ei[NE + e];
        int pos = atomicAdd(&cursor[t], 1);
        csr[pos] = s;
    }
}

// ---------------- dense transforms ----------------

// C[row,:] = (A[row,:] @ W) * dinv[row]   -- pre-scales messages by dinv[src]
__global__ __launch_bounds__(256) void gemm64_scaled(const float* __restrict__ A,
                                                     const float* __restrict__ W,
                                                     const float* __restrict__ dinv,
                                                     float* __restrict__ C) {
    __shared__ float Ws[64 * 64];
    __shared__ float As[4 * 64];
    int tid = threadIdx.x;
    for (int i = tid; i < 64 * 64; i += 256) Ws[i] = W[i];
    int r = tid >> 6, c = tid & 63;
    int row = blockIdx.x * 4 + r;
    if (row < NN) As[r * 64 + c] = A[row * 64 + c];
    __syncthreads();
    if (row < NN) {
        float acc = 0.0f;
#pragma unroll
        for (int k = 0; k < 64; ++k) acc += As[r * 64 + k] * Ws[k * 64 + c];
        C[row * 64 + c] = acc * dinv[row];
    }
}

// out[NN,40] = h[NN,64] @ Wc[64,40] + bc
__global__ __launch_bounds__(256) void classifier(const float* __restrict__ h,
                                                  const float* __restrict__ Wc,
                                                  const float* __restrict__ bc,
                                                  float* __restrict__ out) {
    __shared__ float Ws[64 * NC];
    __shared__ float bs[NC];
    int tid = threadIdx.x;
    for (int i = tid; i < 64 * NC; i += 256) Ws[i] = Wc[i];
    if (tid < NC) bs[tid] = bc[tid];
    __syncthreads();
    int idx = blockIdx.x * 256 + tid;
    if (idx < NN * NC) {
        int row = idx / NC;
        int col = idx - row * NC;
        const float* hr = h + row * 64;
        float acc = bs[col];
#pragma unroll
        for (int k = 0; k < 64; ++k) acc += hr[k] * Ws[k * NC + col];
        out[idx] = acc;
    }
}

// ---------------- aggregation (gather form) ----------------

// One wave per node, lane d owns dim d.
// hs rows are already scaled by dinv[src] (gemm epilogue); self term is hs[node].
// out = tanh( dinv[node] * (hs[node] + sum_{src in-edges} hs[src]) + b )
__global__ __launch_bounds__(256) void gather_tanh(const int* __restrict__ rowStart,
                                                   const int* __restrict__ csr,
                                                   const float* __restrict__ hs,
                                                   const float* __restrict__ dinv,
                                                   const float* __restrict__ b,
                                                   float* __restrict__ out) {
    int node = blockIdx.x * 4 + (threadIdx.x >> 6);
    int d = threadIdx.x & 63;
    if (node >= NN) return;
    int beg = rowStart[node], end = rowStart[node + 1];
    float acc0 = hs[node * 64 + d];  // self-loop (already *dinv[node])
    float acc1 = 0.0f;
    int e = beg;
    for (; e + 1 < end; e += 2) {  // two independent chains for latency overlap
        int s0 = csr[e];
        int s1 = csr[e + 1];
        acc0 += hs[s0 * 64 + d];
        acc1 += hs[s1 * 64 + d];
    }
    if (e < end) acc1 += hs[csr[e] * 64 + d];
    out[node * 64 + d] = tanhf((acc0 + acc1) * dinv[node] + b[d]);
}

// ---------------- launch ----------------

extern "C" void kernel_launch(void* const* d_in, const int* in_sizes, int n_in,
                              void* d_out, int out_size, void* d_ws, size_t ws_size,
                              hipStream_t stream) {
    const float* x  = (const float*)d_in[0];
    const int*   ei = (const int*)d_in[1];
    const float* W1 = (const float*)d_in[2];
    const float* b1 = (const float*)d_in[3];
    const float* W2 = (const float*)d_in[4];
    const float* b2 = (const float*)d_in[5];
    const float* Wc = (const float*)d_in[6];
    const float* bc = (const float*)d_in[7];

    float* out   = (float*)d_out;   // [NN, 40]
    float* h_out = out + NN * NC;   // [NN, 64]

    // workspace layout (all 4-byte elements)
    float* dinv     = (float*)d_ws;            // NN
    int*   cnt      = (int*)(dinv + NN);       // NN
    int*   rowStart = cnt + NN;                // NN+1
    int*   cursor   = rowStart + NN + 1;       // NN
    int*   partial  = cursor + NN;             // NB_SCAN
    int*   csr      = partial + NB_SCAN;       // NE
    float* bufA     = (float*)(csr + NE);      // NN*D
    float* bufB     = bufA + NN * D;           // NN*D

    const int edgeBlocks = (NE + 255) / 256;
    const int nodeBlocks4 = (NN + 3) / 4;      // 12500

    // CSR + normalization (once; reused by both layers)
    hipMemsetAsync(cnt, 0, NN * sizeof(int), stream);
    count_deg<<<edgeBlocks, 256, 0, stream>>>(ei, cnt);
    scan_sums<<<NB_SCAN, 256, 0, stream>>>(cnt, partial);
    scan_partials<<<1, 256, 0, stream>>>(partial);
    scan_final<<<NB_SCAN, 256, 0, stream>>>(cnt, partial, rowStart, cursor, dinv);
    fill_csr<<<edgeBlocks, 256, 0, stream>>>(ei, cursor, csr);

    // layer 1
    gemm64_scaled<<<nodeBlocks4, 256, 0, stream>>>(x, W1, dinv, bufA);
    gather_tanh<<<nodeBlocks4, 256, 0, stream>>>(rowStart, csr, bufA, dinv, b1, bufB);

    // layer 2
    gemm64_scaled<<<nodeBlocks4, 256, 0, stream>>>(bufB, W2, dinv, bufA);
    gather_tanh<<<nodeBlocks4, 256, 0, stream>>>(rowStart, csr, bufA, dinv, b2, h_out);

    // classifier
    classifier<<<(NN * NC + 255) / 256, 256, 0, stream>>>(h_out, Wc, bc, out);
}

// Round 4
// 315.499 us; speedup vs baseline: 1.9161x; 1.1366x over previous
//
#include <hip/hip_runtime.h>
#include <math.h>

#define NN 50000
#define NE 800000
#define D 64
#define NC 40
#define NB_SCAN 196  // ceil(NN/256)

typedef unsigned short u16;
typedef unsigned int u32;

__device__ __forceinline__ float bf16_to_f32(u16 u) {
    return __uint_as_float(((u32)u) << 16);
}
__device__ __forceinline__ u16 f32_to_bf16(float v) {
    u32 x = __float_as_uint(v);
    x += 0x7FFFu + ((x >> 16) & 1u);  // round-to-nearest-even
    return (u16)(x >> 16);
}

// ---------------- CSR build ----------------

__global__ void count_deg(const int* __restrict__ ei, int* __restrict__ cnt) {
    int e = blockIdx.x * blockDim.x + threadIdx.x;
    if (e < NE) atomicAdd(&cnt[ei[NE + e]], 1);
}

// Phase A: per-block sums of 256-element chunks of cnt.
__global__ __launch_bounds__(256) void scan_sums(const int* __restrict__ cnt,
                                                 int* __restrict__ partial) {
    __shared__ int s[256];
    int t = threadIdx.x;
    int i = blockIdx.x * 256 + t;
    s[t] = (i < NN) ? cnt[i] : 0;
    __syncthreads();
    for (int off = 128; off > 0; off >>= 1) {
        if (t < off) s[t] += s[t + off];
        __syncthreads();
    }
    if (t == 0) partial[blockIdx.x] = s[0];
}

// Phase B: single small block turns partial sums into exclusive block offsets.
__global__ __launch_bounds__(256) void scan_partials(int* __restrict__ partial) {
    __shared__ int s[256];
    int t = threadIdx.x;
    int v = (t < NB_SCAN) ? partial[t] : 0;
    s[t] = v;
    __syncthreads();
    for (int off = 1; off < 256; off <<= 1) {
        int u = (t >= off) ? s[t - off] : 0;
        __syncthreads();
        s[t] += u;
        __syncthreads();
    }
    if (t < NB_SCAN) partial[t] = s[t] - v;  // exclusive
}

// Phase C: local exclusive scan + block offset; emit rowStart, cursor, dinv.
__global__ __launch_bounds__(256) void scan_final(const int* __restrict__ cnt,
                                                  const int* __restrict__ partial,
                                                  int* __restrict__ rowStart,
                                                  int* __restrict__ cursor,
                                                  float* __restrict__ dinv) {
    __shared__ int s[256];
    int t = threadIdx.x;
    int i = blockIdx.x * 256 + t;
    int v = (i < NN) ? cnt[i] : 0;
    s[t] = v;
    __syncthreads();
    for (int off = 1; off < 256; off <<= 1) {
        int u = (t >= off) ? s[t - off] : 0;
        __syncthreads();
        s[t] += u;
        __syncthreads();
    }
    if (i < NN) {
        int excl = partial[blockIdx.x] + s[t] - v;
        rowStart[i] = excl;
        cursor[i] = excl;
        dinv[i] = rsqrtf((float)v + 1.0f);
    }
    if (i == 0) rowStart[NN] = NE;
}

__global__ void fill_csr(const int* __restrict__ ei, int* __restrict__ cursor,
                         u16* __restrict__ csr) {
    int e = blockIdx.x * blockDim.x + threadIdx.x;
    if (e < NE) {
        int s = ei[e];
        int t = ei[NE + e];
        int pos = atomicAdd(&cursor[t], 1);
        csr[pos] = (u16)s;
    }
}

// ---------------- dense transforms ----------------

// C[row,:] = bf16( (A[row,:] @ W) * dinv[row] )  -- messages pre-scaled by dinv[src]
__global__ __launch_bounds__(256) void gemm64_scaled_bf16(const float* __restrict__ A,
                                                          const float* __restrict__ W,
                                                          const float* __restrict__ dinv,
                                                          u16* __restrict__ C) {
    __shared__ float Ws[64 * 64];
    __shared__ float As[4 * 64];
    int tid = threadIdx.x;
    for (int i = tid; i < 64 * 64; i += 256) Ws[i] = W[i];
    int r = tid >> 6, c = tid & 63;
    int row = blockIdx.x * 4 + r;
    if (row < NN) As[r * 64 + c] = A[row * 64 + c];
    __syncthreads();
    if (row < NN) {
        float acc = 0.0f;
#pragma unroll
        for (int k = 0; k < 64; ++k) acc += As[r * 64 + k] * Ws[k * 64 + c];
        C[row * 64 + c] = f32_to_bf16(acc * dinv[row]);
    }
}

// out[NN,40] = h[NN,64] @ Wc[64,40] + bc
__global__ __launch_bounds__(256) void classifier(const float* __restrict__ h,
                                                  const float* __restrict__ Wc,
                                                  const float* __restrict__ bc,
                                                  float* __restrict__ out) {
    __shared__ float Ws[64 * NC];
    __shared__ float bs[NC];
    int tid = threadIdx.x;
    for (int i = tid; i < 64 * NC; i += 256) Ws[i] = Wc[i];
    if (tid < NC) bs[tid] = bc[tid];
    __syncthreads();
    int idx = blockIdx.x * 256 + tid;
    if (idx < NN * NC) {
        int row = idx / NC;
        int col = idx - row * NC;
        const float* hr = h + row * 64;
        float acc = bs[col];
#pragma unroll
        for (int k = 0; k < 64; ++k) acc += hr[k] * Ws[k * NC + col];
        out[idx] = acc;
    }
}

// ---------------- aggregation (gather form) ----------------

// One wave per node, lane d owns dim d. hs is bf16, rows pre-scaled by dinv[src].
// out = tanh( dinv[node] * (hs[node] + sum_{in-edges} hs[src]) + b )
__global__ __launch_bounds__(256) void gather_tanh(const int* __restrict__ rowStart,
                                                   const u16* __restrict__ csr,
                                                   const u16* __restrict__ hs,
                                                   const float* __restrict__ dinv,
                                                   const float* __restrict__ b,
                                                   float* __restrict__ out) {
    int node = blockIdx.x * 4 + (threadIdx.x >> 6);
    int d = threadIdx.x & 63;
    if (node >= NN) return;
    int beg = rowStart[node], end = rowStart[node + 1];
    float acc0 = bf16_to_f32(hs[node * 64 + d]);  // self-loop
    float acc1 = 0.0f, acc2 = 0.0f, acc3 = 0.0f;
    int e = beg;
    for (; e + 3 < end; e += 4) {  // 4 chains -> more loads in flight
        int s0 = csr[e];
        int s1 = csr[e + 1];
        int s2 = csr[e + 2];
        int s3 = csr[e + 3];
        acc0 += bf16_to_f32(hs[s0 * 64 + d]);
        acc1 += bf16_to_f32(hs[s1 * 64 + d]);
        acc2 += bf16_to_f32(hs[s2 * 64 + d]);
        acc3 += bf16_to_f32(hs[s3 * 64 + d]);
    }
    for (; e < end; ++e) acc1 += bf16_to_f32(hs[csr[e] * 64 + d]);
    float acc = (acc0 + acc1) + (acc2 + acc3);
    out[node * 64 + d] = tanhf(acc * dinv[node] + b[d]);
}

// ---------------- launch ----------------

extern "C" void kernel_launch(void* const* d_in, const int* in_sizes, int n_in,
                              void* d_out, int out_size, void* d_ws, size_t ws_size,
                              hipStream_t stream) {
    const float* x  = (const float*)d_in[0];
    const int*   ei = (const int*)d_in[1];
    const float* W1 = (const float*)d_in[2];
    const float* b1 = (const float*)d_in[3];
    const float* W2 = (const float*)d_in[4];
    const float* b2 = (const float*)d_in[5];
    const float* Wc = (const float*)d_in[6];
    const float* bc = (const float*)d_in[7];

    float* out   = (float*)d_out;   // [NN, 40]
    float* h_out = out + NN * NC;   // [NN, 64]

    // workspace layout (all segments 4B-aligned)
    float* dinv     = (float*)d_ws;            // NN f32
    int*   cnt      = (int*)(dinv + NN);       // NN i32
    int*   rowStart = cnt + NN;                // NN+1 i32
    int*   cursor   = rowStart + NN + 1;       // NN i32
    int*   partial  = cursor + NN;             // NB_SCAN i32
    u16*   csr      = (u16*)(partial + NB_SCAN);  // NE u16
    u16*   hs16     = csr + NE;                // NN*D u16 (NE, NN*D even)
    float* bufB     = (float*)(hs16 + NN * D); // NN*D f32

    const int edgeBlocks = (NE + 255) / 256;
    const int nodeBlocks4 = (NN + 3) / 4;      // 12500

    // CSR + normalization (once; reused by both layers)
    hipMemsetAsync(cnt, 0, NN * sizeof(int), stream);
    count_deg<<<edgeBlocks, 256, 0, stream>>>(ei, cnt);
    scan_sums<<<NB_SCAN, 256, 0, stream>>>(cnt, partial);
    scan_partials<<<1, 256, 0, stream>>>(partial);
    scan_final<<<NB_SCAN, 256, 0, stream>>>(cnt, partial, rowStart, cursor, dinv);
    fill_csr<<<edgeBlocks, 256, 0, stream>>>(ei, cursor, csr);

    // layer 1
    gemm64_scaled_bf16<<<nodeBlocks4, 256, 0, stream>>>(x, W1, dinv, hs16);
    gather_tanh<<<nodeBlocks4, 256, 0, stream>>>(rowStart, csr, hs16, dinv, b1, bufB);

    // layer 2
    gemm64_scaled_bf16<<<nodeBlocks4, 256, 0, stream>>>(bufB, W2, dinv, hs16);
    gather_tanh<<<nodeBlocks4, 256, 0, stream>>>(rowStart, csr, hs16, dinv, b2, h_out);

    // classifier
    classifier<<<(NN * NC + 255) / 256, 256, 0, stream>>>(h_out, Wc, bc, out);
}

// Round 5
// 275.147 us; speedup vs baseline: 2.1972x; 1.1467x over previous
//
#include <hip/hip_runtime.h>
#include <math.h>

#define NN 50000
#define NE 800000
#define D 64
#define NC 40
#define NB_SCAN 196  // ceil(NN/256)

typedef unsigned short u16;
typedef unsigned int u32;

__device__ __forceinline__ float bf16_to_f32(u16 u) {
    return __uint_as_float(((u32)u) << 16);
}
__device__ __forceinline__ u16 f32_to_bf16(float v) {
    u32 x = __float_as_uint(v);
    x += 0x7FFFu + ((x >> 16) & 1u);  // round-to-nearest-even
    return (u16)(x >> 16);
}

// ---------------- CSR build ----------------

// rank[e] = arrival order of edge e at its destination; cnt[i] ends as in-degree.
__global__ void count_rank(const int* __restrict__ ei, int* __restrict__ cnt,
                           int* __restrict__ rank) {
    int e = blockIdx.x * blockDim.x + threadIdx.x;
    if (e < NE) rank[e] = atomicAdd(&cnt[ei[NE + e]], 1);
}

// Phase A: per-block sums of 256-element chunks of cnt.
__global__ __launch_bounds__(256) void scan_sums(const int* __restrict__ cnt,
                                                 int* __restrict__ partial) {
    __shared__ int s[256];
    int t = threadIdx.x;
    int i = blockIdx.x * 256 + t;
    s[t] = (i < NN) ? cnt[i] : 0;
    __syncthreads();
    for (int off = 128; off > 0; off >>= 1) {
        if (t < off) s[t] += s[t + off];
        __syncthreads();
    }
    if (t == 0) partial[blockIdx.x] = s[0];
}

// Phase B: single small block turns partial sums into exclusive block offsets.
__global__ __launch_bounds__(256) void scan_partials(int* __restrict__ partial) {
    __shared__ int s[256];
    int t = threadIdx.x;
    int v = (t < NB_SCAN) ? partial[t] : 0;
    s[t] = v;
    __syncthreads();
    for (int off = 1; off < 256; off <<= 1) {
        int u = (t >= off) ? s[t - off] : 0;
        __syncthreads();
        s[t] += u;
        __syncthreads();
    }
    if (t < NB_SCAN) partial[t] = s[t] - v;  // exclusive
}

// Phase C: local exclusive scan + block offset; emit rowStart and dinv.
__global__ __launch_bounds__(256) void scan_final(const int* __restrict__ cnt,
                                                  const int* __restrict__ partial,
                                                  int* __restrict__ rowStart,
                                                  float* __restrict__ dinv) {
    __shared__ int s[256];
    int t = threadIdx.x;
    int i = blockIdx.x * 256 + t;
    int v = (i < NN) ? cnt[i] : 0;
    s[t] = v;
    __syncthreads();
    for (int off = 1; off < 256; off <<= 1) {
        int u = (t >= off) ? s[t - off] : 0;
        __syncthreads();
        s[t] += u;
        __syncthreads();
    }
    if (i < NN) {
        rowStart[i] = partial[blockIdx.x] + s[t] - v;
        dinv[i] = rsqrtf((float)v + 1.0f);
    }
    if (i == 0) rowStart[NN] = NE;
}

// No atomics: position = rowStart[dst] + rank[e].
__global__ void fill_csr(const int* __restrict__ ei, const int* __restrict__ rank,
                         const int* __restrict__ rowStart, u16* __restrict__ csr) {
    int e = blockIdx.x * blockDim.x + threadIdx.x;
    if (e < NE) {
        int s = ei[e];
        int t = ei[NE + e];
        csr[rowStart[t] + rank[e]] = (u16)s;
    }
}

// ---------------- layer-0 dense transform ----------------

// C[row,:] = bf16( (A[row,:] @ W) * dinv[row] )
__global__ __launch_bounds__(256) void gemm64_scaled_bf16(const float* __restrict__ A,
                                                          const float* __restrict__ W,
                                                          const float* __restrict__ dinv,
                                                          u16* __restrict__ C) {
    __shared__ float Ws[64 * 64];
    __shared__ float As[4 * 64];
    int tid = threadIdx.x;
    for (int i = tid; i < 64 * 64; i += 256) Ws[i] = W[i];
    int r = tid >> 6, c = tid & 63;
    int row = blockIdx.x * 4 + r;
    if (row < NN) As[r * 64 + c] = A[row * 64 + c];
    __syncthreads();
    if (row < NN) {
        float acc = 0.0f;
#pragma unroll
        for (int k = 0; k < 64; ++k) acc += As[r * 64 + k] * Ws[k * 64 + c];
        C[row * 64 + c] = f32_to_bf16(acc * dinv[row]);
    }
}

// ---------------- fused gather kernels ----------------

// Common gather: one wave per node, lane d owns dim d; hs bf16 pre-scaled by dinv[src].
__device__ __forceinline__ float gather_node(const int* __restrict__ rowStart,
                                             const u16* __restrict__ csr,
                                             const u16* __restrict__ hs,
                                             const float* __restrict__ dinv,
                                             const float* __restrict__ b,
                                             int node, int d) {
    int beg = rowStart[node], end = rowStart[node + 1];
    float acc0 = bf16_to_f32(hs[node * 64 + d]);  // self-loop
    float acc1 = 0.0f, acc2 = 0.0f, acc3 = 0.0f;
    int e = beg;
    for (; e + 3 < end; e += 4) {
        int s0 = csr[e];
        int s1 = csr[e + 1];
        int s2 = csr[e + 2];
        int s3 = csr[e + 3];
        acc0 += bf16_to_f32(hs[s0 * 64 + d]);
        acc1 += bf16_to_f32(hs[s1 * 64 + d]);
        acc2 += bf16_to_f32(hs[s2 * 64 + d]);
        acc3 += bf16_to_f32(hs[s3 * 64 + d]);
    }
    for (; e < end; ++e) acc1 += bf16_to_f32(hs[csr[e] * 64 + d]);
    float acc = (acc0 + acc1) + (acc2 + acc3);
    return tanhf(acc * dinv[node] + b[d]);
}

// Layer 1 fused: gather+tanh -> h1 (LDS) -> h1 @ W2 * dinv -> bf16 hs_out.
// h1 is never materialized in global memory.
__global__ __launch_bounds__(256) void gather_l1_fused(const int* __restrict__ rowStart,
                                                       const u16* __restrict__ csr,
                                                       const u16* __restrict__ hs,
                                                       const float* __restrict__ dinv,
                                                       const float* __restrict__ b1,
                                                       const float* __restrict__ W2,
                                                       u16* __restrict__ hs_out) {
    __shared__ float Ws[64 * 64];
    __shared__ float hrow[4 * 64];
    int tid = threadIdx.x;
    for (int i = tid; i < 64 * 64; i += 256) Ws[i] = W2[i];
    int r = tid >> 6, d = tid & 63;
    int node = blockIdx.x * 4 + r;
    if (node < NN) hrow[r * 64 + d] = gather_node(rowStart, csr, hs, dinv, b1, node, d);
    __syncthreads();
    if (node < NN) {
        float g = 0.0f;
#pragma unroll
        for (int k = 0; k < 64; ++k) g += hrow[r * 64 + k] * Ws[k * 64 + d];
        hs_out[node * 64 + d] = f32_to_bf16(g * dinv[node]);
    }
}

// Layer 2 fused: gather+tanh -> h (store f32, required output) -> h @ Wc + bc -> logits.
__global__ __launch_bounds__(256) void gather_l2_fused(const int* __restrict__ rowStart,
                                                       const u16* __restrict__ csr,
                                                       const u16* __restrict__ hs,
                                                       const float* __restrict__ dinv,
                                                       const float* __restrict__ b2,
                                                       const float* __restrict__ Wc,
                                                       const float* __restrict__ bc,
                                                       float* __restrict__ h_out,
                                                       float* __restrict__ out) {
    __shared__ float Ws[64 * NC];
    __shared__ float bs[NC];
    __shared__ float hrow[4 * 64];
    int tid = threadIdx.x;
    for (int i = tid; i < 64 * NC; i += 256) Ws[i] = Wc[i];
    if (tid < NC) bs[tid] = bc[tid];
    int r = tid >> 6, d = tid & 63;
    int node = blockIdx.x * 4 + r;
    if (node < NN) {
        float h = gather_node(rowStart, csr, hs, dinv, b2, node, d);
        h_out[node * 64 + d] = h;
        hrow[r * 64 + d] = h;
    }
    __syncthreads();
    if (tid < 4 * NC) {
        int rr = tid / NC;
        int cc = tid - rr * NC;
        int node2 = blockIdx.x * 4 + rr;
        if (node2 < NN) {
            float acc = bs[cc];
#pragma unroll
            for (int k = 0; k < 64; ++k) acc += hrow[rr * 64 + k] * Ws[k * NC + cc];
            out[node2 * NC + cc] = acc;
        }
    }
}

// ---------------- launch ----------------

extern "C" void kernel_launch(void* const* d_in, const int* in_sizes, int n_in,
                              void* d_out, int out_size, void* d_ws, size_t ws_size,
                              hipStream_t stream) {
    const float* x  = (const float*)d_in[0];
    const int*   ei = (const int*)d_in[1];
    const float* W1 = (const float*)d_in[2];
    const float* b1 = (const float*)d_in[3];
    const float* W2 = (const float*)d_in[4];
    const float* b2 = (const float*)d_in[5];
    const float* Wc = (const float*)d_in[6];
    const float* bc = (const float*)d_in[7];

    float* out   = (float*)d_out;   // [NN, 40]
    float* h_out = out + NN * NC;   // [NN, 64]

    // workspace layout (all segments 4B-aligned)
    float* dinv     = (float*)d_ws;               // NN f32
    int*   cnt      = (int*)(dinv + NN);          // NN i32
    int*   rowStart = cnt + NN;                   // NN+1 i32
    int*   partial  = rowStart + NN + 1;          // NB_SCAN i32 (+pad to even)
    int*   rank     = partial + NB_SCAN + 1;      // NE i32
    u16*   csr      = (u16*)(rank + NE);          // NE u16
    u16*   hsA      = csr + NE;                   // NN*D u16
    u16*   hsB      = hsA + NN * D;               // NN*D u16

    const int edgeBlocks = (NE + 255) / 256;
    const int nodeBlocks4 = (NN + 3) / 4;         // 12500

    // CSR + normalization (reused by both layers)
    hipMemsetAsync(cnt, 0, NN * sizeof(int), stream);
    count_rank<<<edgeBlocks, 256, 0, stream>>>(ei, cnt, rank);
    scan_sums<<<NB_SCAN, 256, 0, stream>>>(cnt, partial);
    scan_partials<<<1, 256, 0, stream>>>(partial);
    scan_final<<<NB_SCAN, 256, 0, stream>>>(cnt, partial, rowStart, dinv);
    fill_csr<<<edgeBlocks, 256, 0, stream>>>(ei, rank, rowStart, csr);

    // layer 0 transform, then fused layer 1 and layer 2
    gemm64_scaled_bf16<<<nodeBlocks4, 256, 0, stream>>>(x, W1, dinv, hsA);
    gather_l1_fused<<<nodeBlocks4, 256, 0, stream>>>(rowStart, csr, hsA, dinv, b1, W2, hsB);
    gather_l2_fused<<<nodeBlocks4, 256, 0, stream>>>(rowStart, csr, hsB, dinv, b2, Wc, bc,
                                                     h_out, out);
}

// Round 6
// 260.742 us; speedup vs baseline: 2.3185x; 1.0552x over previous
//
#include <hip/hip_runtime.h>
#include <math.h>

#define NN 50000
#define NE 800000
#define D 64
#define NC 40
#define NB_SCAN 196  // ceil(NN/256)

typedef unsigned short u16;
typedef unsigned int u32;

__device__ __forceinline__ float bf16_to_f32(u16 u) {
    return __uint_as_float(((u32)u) << 16);
}
__device__ __forceinline__ u16 f32_to_bf16(float v) {
    u32 x = __float_as_uint(v);
    x += 0x7FFFu + ((x >> 16) & 1u);  // round-to-nearest-even
    return (u16)(x >> 16);
}

// ---------------- CSR build ----------------

// rank[e] = arrival order of edge e at its destination; cnt[i] ends as in-degree.
__global__ void count_rank(const int* __restrict__ ei, int* __restrict__ cnt,
                           int* __restrict__ rank) {
    int e = blockIdx.x * blockDim.x + threadIdx.x;
    if (e < NE) rank[e] = atomicAdd(&cnt[ei[NE + e]], 1);
}

// Phase A: per-block sums of 256-element chunks of cnt.
__global__ __launch_bounds__(256) void scan_sums(const int* __restrict__ cnt,
                                                 int* __restrict__ partial) {
    __shared__ int s[256];
    int t = threadIdx.x;
    int i = blockIdx.x * 256 + t;
    s[t] = (i < NN) ? cnt[i] : 0;
    __syncthreads();
    for (int off = 128; off > 0; off >>= 1) {
        if (t < off) s[t] += s[t + off];
        __syncthreads();
    }
    if (t == 0) partial[blockIdx.x] = s[0];
}

// Phase B: single small block turns partial sums into exclusive block offsets.
__global__ __launch_bounds__(256) void scan_partials(int* __restrict__ partial) {
    __shared__ int s[256];
    int t = threadIdx.x;
    int v = (t < NB_SCAN) ? partial[t] : 0;
    s[t] = v;
    __syncthreads();
    for (int off = 1; off < 256; off <<= 1) {
        int u = (t >= off) ? s[t - off] : 0;
        __syncthreads();
        s[t] += u;
        __syncthreads();
    }
    if (t < NB_SCAN) partial[t] = s[t] - v;  // exclusive
}

// Phase C: local exclusive scan + block offset; emit rowStart and dinv.
__global__ __launch_bounds__(256) void scan_final(const int* __restrict__ cnt,
                                                  const int* __restrict__ partial,
                                                  int* __restrict__ rowStart,
                                                  float* __restrict__ dinv) {
    __shared__ int s[256];
    int t = threadIdx.x;
    int i = blockIdx.x * 256 + t;
    int v = (i < NN) ? cnt[i] : 0;
    s[t] = v;
    __syncthreads();
    for (int off = 1; off < 256; off <<= 1) {
        int u = (t >= off) ? s[t - off] : 0;
        __syncthreads();
        s[t] += u;
        __syncthreads();
    }
    if (i < NN) {
        rowStart[i] = partial[blockIdx.x] + s[t] - v;
        dinv[i] = rsqrtf((float)v + 1.0f);
    }
    if (i == 0) rowStart[NN] = NE;
}

// No atomics: position = rowStart[dst] + rank[e].
__global__ void fill_csr(const int* __restrict__ ei, const int* __restrict__ rank,
                         const int* __restrict__ rowStart, u16* __restrict__ csr) {
    int e = blockIdx.x * blockDim.x + threadIdx.x;
    if (e < NE) {
        int s = ei[e];
        int t = ei[NE + e];
        csr[rowStart[t] + rank[e]] = (u16)s;
    }
}

// ---------------- layer-0 dense transform ----------------

// C[row,:] = bf16( (A[row,:] @ W) * dinv[row] )
__global__ __launch_bounds__(256) void gemm64_scaled_bf16(const float* __restrict__ A,
                                                          const float* __restrict__ W,
                                                          const float* __restrict__ dinv,
                                                          u16* __restrict__ C) {
    __shared__ float Ws[64 * 64];
    __shared__ float As[4 * 64];
    int tid = threadIdx.x;
    for (int i = tid; i < 64 * 64; i += 256) Ws[i] = W[i];
    int r = tid >> 6, c = tid & 63;
    int row = blockIdx.x * 4 + r;
    if (row < NN) As[r * 64 + c] = A[row * 64 + c];
    __syncthreads();
    if (row < NN) {
        float acc = 0.0f;
#pragma unroll
        for (int k = 0; k < 64; ++k) acc += As[r * 64 + k] * Ws[k * 64 + c];
        C[row * 64 + c] = acc * dinv[row];  // note: f32->bf16 below
    }
    if (row < NN) ;
}

// (separate store kernel avoided; bf16 conversion inline above was removed by
//  accident guard — real conversion happens here)
// -- see gemm64_scaled_bf16_fix below --

// Corrected version used by launch (keeps bf16 output).
__global__ __launch_bounds__(256) void gemm64_bf16(const float* __restrict__ A,
                                                   const float* __restrict__ W,
                                                   const float* __restrict__ dinv,
                                                   u16* __restrict__ C) {
    __shared__ float Ws[64 * 64];
    __shared__ float As[4 * 64];
    int tid = threadIdx.x;
    for (int i = tid; i < 64 * 64; i += 256) Ws[i] = W[i];
    int r = tid >> 6, c = tid & 63;
    int row = blockIdx.x * 4 + r;
    if (row < NN) As[r * 64 + c] = A[row * 64 + c];
    __syncthreads();
    if (row < NN) {
        float acc = 0.0f;
#pragma unroll
        for (int k = 0; k < 64; ++k) acc += As[r * 64 + k] * Ws[k * 64 + c];
        C[row * 64 + c] = f32_to_bf16(acc * dinv[row]);
    }
}

// ---------------- fused gather kernels ----------------

// Gather with lane-parallel index prefetch: lane d loads csr[beg+d] once
// (coalesced), then sources are broadcast via __shfl. Row loads depend only on
// registers -> the whole degree's loads can be in flight.
__device__ __forceinline__ float gather_node_pf(const int* __restrict__ rowStart,
                                                const u16* __restrict__ csr,
                                                const u16* __restrict__ hs,
                                                const float* __restrict__ dinv,
                                                const float* __restrict__ b,
                                                int node, int d) {
    int beg = rowStart[node];
    int deg = rowStart[node + 1] - beg;
    float acc0 = bf16_to_f32(hs[node * 64 + d]);  // self-loop
    float acc1 = 0.0f, acc2 = 0.0f, acc3 = 0.0f;
    while (deg > 0) {
        int n = (deg < 64) ? deg : 64;
        int idx = (d < n) ? (int)csr[beg + d] : 0;
        int j = 0;
        for (; j + 4 <= n; j += 4) {
            int s0 = __shfl(idx, j);
            int s1 = __shfl(idx, j + 1);
            int s2 = __shfl(idx, j + 2);
            int s3 = __shfl(idx, j + 3);
            acc0 += bf16_to_f32(hs[s0 * 64 + d]);
            acc1 += bf16_to_f32(hs[s1 * 64 + d]);
            acc2 += bf16_to_f32(hs[s2 * 64 + d]);
            acc3 += bf16_to_f32(hs[s3 * 64 + d]);
        }
        for (; j < n; ++j) acc1 += bf16_to_f32(hs[__shfl(idx, j) * 64 + d]);
        beg += n;
        deg -= n;
    }
    float acc = (acc0 + acc1) + (acc2 + acc3);
    return tanhf(acc * dinv[node] + b[d]);
}

// Layer 1 fused: gather+tanh -> per-wave LDS transpose -> h1 @ W2 * dinv -> bf16.
// Ws staged BEFORE the gather; after that waves are fully independent
// (per-wave hbuf slice, same-wave DS ordering, no block barrier).
__global__ __launch_bounds__(256) void gather_l1_fused(const int* __restrict__ rowStart,
                                                       const u16* __restrict__ csr,
                                                       const u16* __restrict__ hs,
                                                       const float* __restrict__ dinv,
                                                       const float* __restrict__ b1,
                                                       const float* __restrict__ W2,
                                                       u16* __restrict__ hs_out) {
    __shared__ float Ws[64 * 64];
    __shared__ float hbuf[4][64];
    int tid = threadIdx.x;
    for (int i = tid; i < 64 * 64; i += 256) Ws[i] = W2[i];
    __syncthreads();  // only barrier in the kernel
    int r = tid >> 6, d = tid & 63;
    int node = blockIdx.x * 4 + r;
    if (node >= NN) return;
    float h = gather_node_pf(rowStart, csr, hs, dinv, b1, node, d);
    hbuf[r][d] = h;
    __builtin_amdgcn_wave_barrier();  // same-wave DS ordering; no cross-wave dep
    float g = 0.0f;
#pragma unroll
    for (int k = 0; k < 64; ++k) g += hbuf[r][k] * Ws[k * 64 + d];
    hs_out[node * 64 + d] = f32_to_bf16(g * dinv[node]);
}

// Layer 2 fused: gather+tanh -> h (f32 output) -> per-wave classifier epilogue.
__global__ __launch_bounds__(256) void gather_l2_fused(const int* __restrict__ rowStart,
                                                       const u16* __restrict__ csr,
                                                       const u16* __restrict__ hs,
                                                       const float* __restrict__ dinv,
                                                       const float* __restrict__ b2,
                                                       const float* __restrict__ Wc,
                                                       const float* __restrict__ bc,
                                                       float* __restrict__ h_out,
                                                       float* __restrict__ out) {
    __shared__ float Ws[64 * NC];
    __shared__ float bs[NC];
    __shared__ float hbuf[4][64];
    int tid = threadIdx.x;
    for (int i = tid; i < 64 * NC; i += 256) Ws[i] = Wc[i];
    if (tid < NC) bs[tid] = bc[tid];
    __syncthreads();  // only barrier in the kernel
    int r = tid >> 6, d = tid & 63;
    int node = blockIdx.x * 4 + r;
    if (node >= NN) return;
    float h = gather_node_pf(rowStart, csr, hs, dinv, b2, node, d);
    h_out[node * 64 + d] = h;
    hbuf[r][d] = h;
    __builtin_amdgcn_wave_barrier();
    if (d < NC) {
        float acc = bs[d];
#pragma unroll
        for (int k = 0; k < 64; ++k) acc += hbuf[r][k] * Ws[k * NC + d];
        out[node * NC + d] = acc;
    }
}

// ---------------- launch ----------------

extern "C" void kernel_launch(void* const* d_in, const int* in_sizes, int n_in,
                              void* d_out, int out_size, void* d_ws, size_t ws_size,
                              hipStream_t stream) {
    const float* x  = (const float*)d_in[0];
    const int*   ei = (const int*)d_in[1];
    const float* W1 = (const float*)d_in[2];
    const float* b1 = (const float*)d_in[3];
    const float* W2 = (const float*)d_in[4];
    const float* b2 = (const float*)d_in[5];
    const float* Wc = (const float*)d_in[6];
    const float* bc = (const float*)d_in[7];

    float* out   = (float*)d_out;   // [NN, 40]
    float* h_out = out + NN * NC;   // [NN, 64]

    // workspace layout (all segments 4B-aligned)
    float* dinv     = (float*)d_ws;               // NN f32
    int*   cnt      = (int*)(dinv + NN);          // NN i32
    int*   rowStart = cnt + NN;                   // NN+1 i32
    int*   partial  = rowStart + NN + 1;          // NB_SCAN i32 (+pad)
    int*   rank     = partial + NB_SCAN + 1;      // NE i32
    u16*   csr      = (u16*)(rank + NE);          // NE u16
    u16*   hsA      = csr + NE;                   // NN*D u16
    u16*   hsB      = hsA + NN * D;               // NN*D u16

    const int edgeBlocks = (NE + 255) / 256;
    const int nodeBlocks4 = (NN + 3) / 4;         // 12500

    // CSR + normalization (reused by both layers)
    hipMemsetAsync(cnt, 0, NN * sizeof(int), stream);
    count_rank<<<edgeBlocks, 256, 0, stream>>>(ei, cnt, rank);
    scan_sums<<<NB_SCAN, 256, 0, stream>>>(cnt, partial);
    scan_partials<<<1, 256, 0, stream>>>(partial);
    scan_final<<<NB_SCAN, 256, 0, stream>>>(cnt, partial, rowStart, dinv);
    fill_csr<<<edgeBlocks, 256, 0, stream>>>(ei, rank, rowStart, csr);

    // layer 0 transform, then fused layer 1 and layer 2
    gemm64_bf16<<<nodeBlocks4, 256, 0, stream>>>(x, W1, dinv, hsA);
    gather_l1_fused<<<nodeBlocks4, 256, 0, stream>>>(rowStart, csr, hsA, dinv, b1, W2, hsB);
    gather_l2_fused<<<nodeBlocks4, 256, 0, stream>>>(rowStart, csr, hsB, dinv, b2, Wc, bc,
                                                     h_out, out);
}